// Round 7
// baseline (2180.346 us; speedup 1.0000x reference)
//
#include <hip/hip_runtime.h>

__global__ void k_fill(unsigned* p, int n, unsigned v) {
    int i = blockIdx.x * blockDim.x + threadIdx.x;
    if (i < n) p[i] = v;
}

// ---------------- CSR build (graph identical across layers; built once) ----------------
__global__ void k_hist(const int* __restrict__ ei, int E, int* __restrict__ deg) {
    int e = blockIdx.x * blockDim.x + threadIdx.x;
    if (e < E) atomicAdd(&deg[ei[E + e]], 1);
}

__global__ void k_scan_blocks(const int* __restrict__ deg, int N,
                              int* __restrict__ excl, int* __restrict__ parts) {
    __shared__ int s[256];
    int t = threadIdx.x, i = blockIdx.x * 256 + t;
    int v = (i < N) ? deg[i] : 0;
    s[t] = v;
    __syncthreads();
    int acc = v;
    for (int off = 1; off < 256; off <<= 1) {
        int add = (t >= off) ? s[t - off] : 0;
        __syncthreads();
        acc += add;
        s[t] = acc;
        __syncthreads();
    }
    if (i < N) excl[i] = acc - v;
    if (t == 255) parts[blockIdx.x] = acc;
}

__global__ void k_scan_parts(int* __restrict__ parts, int nb) {
    __shared__ int s[256];
    int t = threadIdx.x;
    int v = (t < nb) ? parts[t] : 0;
    s[t] = v;
    __syncthreads();
    int acc = v;
    for (int off = 1; off < 256; off <<= 1) {
        int add = (t >= off) ? s[t - off] : 0;
        __syncthreads();
        acc += add;
        s[t] = acc;
        __syncthreads();
    }
    if (t < nb) parts[t] = acc - v;
}

__global__ void k_scan_add(const int* __restrict__ excl, const int* __restrict__ parts,
                           int* __restrict__ row_ptr, int* __restrict__ cursor, int N) {
    int i = blockIdx.x * blockDim.x + threadIdx.x;
    if (i >= N) return;
    int r = excl[i] + parts[i >> 8];
    row_ptr[i] = r;
    cursor[i] = r;
}

__global__ void k_scatter(const int* __restrict__ ei, int E, int* __restrict__ cursor,
                          int2* __restrict__ elist) {
    int e = blockIdx.x * blockDim.x + threadIdx.x;
    if (e >= E) return;
    int d = ei[E + e];
    int j = atomicAdd(&cursor[d], 1);
    elist[j] = make_int2(ei[e], e);
}

// permute edge_attr into CSR order: ea_s[j] = ea[elist[j].y]  (8 threads per edge)
__global__ void k_reorder(const int2* __restrict__ elist, const float* __restrict__ ea, int E,
                          float4* __restrict__ ea_s) {
    int idx = blockIdx.x * blockDim.x + threadIdx.x;
    int j = idx >> 3, q = idx & 7;
    if (j >= E) return;
    ea_s[(size_t)j * 8 + q] = ((const float4*)ea)[(size_t)elist[j].y * 8 + q];
}

// ---------------- Dual GEMM: out{l,r} = A @ W{l,r} + b{l,r} ----------------
template <int M, int RW>
__global__ __launch_bounds__(256) void k_gemm2(const float* __restrict__ A,
                                               const float* __restrict__ Wl, const float* __restrict__ bl,
                                               const float* __restrict__ Wr, const float* __restrict__ br,
                                               float* __restrict__ outl, float* __restrict__ outr) {
    constexpr int TX = M / 4;
    __shared__ float sA[32][68];
    __shared__ float sW[32][M];
    const float* W    = blockIdx.y ? Wr : Wl;
    const float* bias = blockIdx.y ? br : bl;
    float* out        = blockIdx.y ? outr : outl;
    int t = threadIdx.x;
    int tx = t % TX, ty = t / TX;
    int r0 = blockIdx.x * 64;
    float acc[RW][4] = {};
    for (int kt = 0; kt < 128; kt += 32) {
        for (int l = t; l < 512; l += 256) {
            int row = l >> 3, kq = (l & 7) << 2;
            float4 a = *(const float4*)&A[(size_t)(r0 + row) * 128 + kt + kq];
            sA[kq + 0][row] = a.x; sA[kq + 1][row] = a.y;
            sA[kq + 2][row] = a.z; sA[kq + 3][row] = a.w;
        }
        for (int l = t; l < 32 * M / 4; l += 256) {
            int kk = (l * 4) / M, cc = (l * 4) % M;
            *(float4*)&sW[kk][cc] = *(const float4*)&W[(size_t)(kt + kk) * M + cc];
        }
        __syncthreads();
#pragma unroll
        for (int k = 0; k < 32; k++) {
            float4 w = *(float4*)&sW[k][tx * 4];
            float ar[RW];
#pragma unroll
            for (int i = 0; i < RW; i += 4) {
                float4 a = *(float4*)&sA[k][ty * RW + i];
                ar[i] = a.x; ar[i + 1] = a.y; ar[i + 2] = a.z; ar[i + 3] = a.w;
            }
#pragma unroll
            for (int i = 0; i < RW; i++) {
                acc[i][0] += ar[i] * w.x; acc[i][1] += ar[i] * w.y;
                acc[i][2] += ar[i] * w.z; acc[i][3] += ar[i] * w.w;
            }
        }
        __syncthreads();
    }
    float4 b = *(const float4*)&bias[tx * 4];
#pragma unroll
    for (int i = 0; i < RW; i++) {
        float4 v;
        v.x = acc[i][0] + b.x; v.y = acc[i][1] + b.y;
        v.z = acc[i][2] + b.z; v.w = acc[i][3] + b.w;
        *(float4*)&out[(size_t)(r0 + ty * RW + i) * M + tx * 4] = v;
    }
}

// ---------------- Fused per-dst GATv2 aggregation (CSR, zero atomics) ----------------
// Wave per node (both heads in-wave: ea loads shared). Edges processed in groups of EG;
// all EG*H logit partial-sums reduced in ONE interleaved 6-step butterfly (chains pipelined),
// amortizing the ~250-cyc shuffle-chain latency over EG edges. Gathered xl kept in regs.
template <int H, bool RELU, bool SORTED>
__global__ __launch_bounds__(256, 4) void k_agg(const float* __restrict__ xl, const float* __restrict__ xr,
                                                const float* __restrict__ ea, const float4* __restrict__ ea_s,
                                                const int2* __restrict__ elist,
                                                const int* __restrict__ row_ptr, const int* __restrict__ deg,
                                                const float* __restrict__ We, const float* __restrict__ att,
                                                const float* __restrict__ bias, float* __restrict__ out, int N) {
    constexpr int HC = H * 64;
    constexpr int EG = (H == 2) ? 4 : 8;   // 8 reduce chains in flight either way
    int tid = threadIdx.x, wv = tid >> 6, lane = tid & 63;
    float rWe0[32], rWe1[H == 2 ? 32 : 1];
#pragma unroll
    for (int k = 0; k < 32; k++) rWe0[k] = We[k * HC + lane];
    if constexpr (H == 2) {
#pragma unroll
        for (int k = 0; k < 32; k++) rWe1[k] = We[k * HC + 64 + lane];
    }
    float att0 = att[lane], b0 = bias[lane];
    float att1 = 0.f, b1 = 0.f;
    if constexpr (H == 2) { att1 = att[64 + lane]; b1 = bias[64 + lane]; }
    int n = blockIdx.x * 4 + wv;
    if (n >= N) return;
    int start = row_ptr[n], d = deg[n];
    float xr0 = xr[(size_t)n * HC + lane];
    float xr1 = (H == 2) ? xr[(size_t)n * HC + 64 + lane] : 0.f;
    float acc0 = 0.f, acc1 = 0.f, den0 = 0.f, den1 = 0.f;
    int j = 0;
    for (; j + EG <= d; j += EG) {
        float p[EG * H];
        float xl0[EG];
        float xl1[H == 2 ? EG : 1];
#pragma unroll
        for (int u = 0; u < EG; u++) {
            int2 sp = elist[start + j + u];
            const float4* eap = SORTED ? (ea_s + (size_t)(start + j + u) * 8)
                                       : (const float4*)(ea + (size_t)sp.y * 32);
            const float* xls = xl + (size_t)sp.x * HC;
            xl0[u] = xls[lane];
            if constexpr (H == 2) xl1[u] = xls[64 + lane];
            float ee0 = 0.f, ee1 = 0.f;
#pragma unroll
            for (int kq = 0; kq < 8; kq++) {
                float4 v = eap[kq];
                ee0 = fmaf(v.x, rWe0[kq * 4 + 0], ee0);
                ee0 = fmaf(v.y, rWe0[kq * 4 + 1], ee0);
                ee0 = fmaf(v.z, rWe0[kq * 4 + 2], ee0);
                ee0 = fmaf(v.w, rWe0[kq * 4 + 3], ee0);
                if constexpr (H == 2) {
                    ee1 = fmaf(v.x, rWe1[kq * 4 + 0], ee1);
                    ee1 = fmaf(v.y, rWe1[kq * 4 + 1], ee1);
                    ee1 = fmaf(v.z, rWe1[kq * 4 + 2], ee1);
                    ee1 = fmaf(v.w, rWe1[kq * 4 + 3], ee1);
                }
            }
            float v0 = xl0[u] + xr0 + ee0;
            v0 = v0 > 0.f ? v0 : 0.2f * v0;
            p[u] = att0 * v0;
            if constexpr (H == 2) {
                float v1 = xl1[u] + xr1 + ee1;
                v1 = v1 > 0.f ? v1 : 0.2f * v1;
                p[EG + u] = att1 * v1;
            }
        }
        // interleaved butterfly: EG*H independent chains share one 6-step latency
#pragma unroll
        for (int m = 32; m; m >>= 1) {
#pragma unroll
            for (int u = 0; u < EG * H; u++) p[u] += __shfl_xor(p[u], m);
        }
#pragma unroll
        for (int u = 0; u < EG; u++) {
            float ex0 = __expf(p[u]);
            acc0 = fmaf(ex0, xl0[u], acc0);
            den0 += ex0;
            if constexpr (H == 2) {
                float ex1 = __expf(p[EG + u]);
                acc1 = fmaf(ex1, xl1[u], acc1);
                den1 += ex1;
            }
        }
    }
    for (; j < d; j++) {   // remainder, single edge
        int2 sp = elist[start + j];
        const float4* eap = SORTED ? (ea_s + (size_t)(start + j) * 8)
                                   : (const float4*)(ea + (size_t)sp.y * 32);
        const float* xls = xl + (size_t)sp.x * HC;
        float xlA = xls[lane];
        float xlB = (H == 2) ? xls[64 + lane] : 0.f;
        float ee0 = 0.f, ee1 = 0.f;
#pragma unroll
        for (int kq = 0; kq < 8; kq++) {
            float4 v = eap[kq];
            ee0 = fmaf(v.x, rWe0[kq * 4 + 0], ee0);
            ee0 = fmaf(v.y, rWe0[kq * 4 + 1], ee0);
            ee0 = fmaf(v.z, rWe0[kq * 4 + 2], ee0);
            ee0 = fmaf(v.w, rWe0[kq * 4 + 3], ee0);
            if constexpr (H == 2) {
                ee1 = fmaf(v.x, rWe1[kq * 4 + 0], ee1);
                ee1 = fmaf(v.y, rWe1[kq * 4 + 1], ee1);
                ee1 = fmaf(v.z, rWe1[kq * 4 + 2], ee1);
                ee1 = fmaf(v.w, rWe1[kq * 4 + 3], ee1);
            }
        }
        float v0 = xlA + xr0 + ee0;
        v0 = v0 > 0.f ? v0 : 0.2f * v0;
        float p0 = att0 * v0, p1 = 0.f;
        if constexpr (H == 2) {
            float v1 = xlB + xr1 + ee1;
            v1 = v1 > 0.f ? v1 : 0.2f * v1;
            p1 = att1 * v1;
        }
#pragma unroll
        for (int m = 32; m; m >>= 1) {
            p0 += __shfl_xor(p0, m);
            if constexpr (H == 2) p1 += __shfl_xor(p1, m);
        }
        float ex0 = __expf(p0);
        acc0 = fmaf(ex0, xlA, acc0);
        den0 += ex0;
        if constexpr (H == 2) {
            float ex1 = __expf(p1);
            acc1 = fmaf(ex1, xlB, acc1);
            den1 += ex1;
        }
    }
    float o0 = acc0 / (den0 + 1e-16f) + b0;
    if (RELU) o0 = o0 > 0.f ? o0 : 0.f;
    out[(size_t)n * HC + lane] = o0;
    if constexpr (H == 2) {
        float o1 = acc1 / (den1 + 1e-16f) + b1;
        if (RELU) o1 = o1 > 0.f ? o1 : 0.f;
        out[(size_t)n * HC + 64 + lane] = o1;
    }
}

// ---------------- gate MLP: gate[n] = exp(relu(h[n]@G1w+G1b)@G2w + G2b) ----------------
__global__ __launch_bounds__(256) void k_gate(const float* __restrict__ h, const float* __restrict__ G1w,
                                              const float* __restrict__ G1b, const float* __restrict__ G2w,
                                              const float* __restrict__ G2b,
                                              float* __restrict__ gate, int N) {
    __shared__ float sH[64][64];
    __shared__ float part[64][2];
    int t = threadIdx.x;
    int n0 = blockIdx.x * 64;
    for (int l = t; l < 1024; l += 256) {
        float4 v = ((const float4*)(h + (size_t)n0 * 64))[l];
        int n = l >> 4, kq = (l & 15) << 2;
        *(float4*)&sH[n][kq] = v;
    }
    int c = t & 127, half = t >> 7;
    float rW[64];
#pragma unroll
    for (int k = 0; k < 64; k++) rW[k] = G1w[k * 128 + c];
    float g1b = G1b[c], g2w = G2w[c];
    __syncthreads();
    for (int nn = 0; nn < 32; nn++) {
        int n = half * 32 + nn;
        float acc = g1b;
#pragma unroll
        for (int k = 0; k < 64; k += 4) {
            float4 hv = *(const float4*)&sH[n][k];
            acc = fmaf(hv.x, rW[k], acc);
            acc = fmaf(hv.y, rW[k + 1], acc);
            acc = fmaf(hv.z, rW[k + 2], acc);
            acc = fmaf(hv.w, rW[k + 3], acc);
        }
        acc = acc > 0.f ? acc : 0.f;
        float p = acc * g2w;
#pragma unroll
        for (int m = 32; m; m >>= 1) p += __shfl_xor(p, m);
        if ((t & 63) == 0) part[n][(t >> 6) & 1] = p;
    }
    __syncthreads();
    if (t < 64) gate[n0 + t] = __expf(part[t][0] + part[t][1] + G2b[0]);
}

// ---------------- pooling: one block per graph (batch sorted -> binary search range) ----------------
__global__ __launch_bounds__(256) void k_pool(const float* __restrict__ h, const float* __restrict__ gate,
                                              const int* __restrict__ batch,
                                              float* __restrict__ pooled, int N) {
    int g = blockIdx.x;
    int lo = 0, hi = N;
    while (lo < hi) { int mid = (lo + hi) >> 1; if (batch[mid] < g) lo = mid + 1; else hi = mid; }
    int start = lo;
    lo = 0; hi = N;
    while (lo < hi) { int mid = (lo + hi) >> 1; if (batch[mid] < g + 1) lo = mid + 1; else hi = mid; }
    int end = lo;
    int t = threadIdx.x, wv = t >> 6, lane = t & 63;
    float acc = 0.f, den = 0.f;
    for (int n = start + wv; n < end; n += 4) {
        float gv = gate[n];
        acc = fmaf(gv, h[(size_t)n * 64 + lane], acc);
        den += gv;
    }
    __shared__ float sacc[4][64];
    __shared__ float sden[4];
    sacc[wv][lane] = acc;
    if (lane == 0) sden[wv] = den;
    __syncthreads();
    if (wv == 0) {
        float a = sacc[0][lane] + sacc[1][lane] + sacc[2][lane] + sacc[3][lane];
        float d = sden[0] + sden[1] + sden[2] + sden[3] + 1e-16f;
        pooled[g * 64 + lane] = a / d;
    }
}

__global__ void k_final(const float* __restrict__ pooled, const float* __restrict__ Wreg,
                        const float* __restrict__ breg, float* __restrict__ out) {
    int g = threadIdx.x;
    float acc = breg[0];
    for (int c = 0; c < 64; c++) acc += pooled[g * 64 + c] * Wreg[c];
    out[g] = acc;
}

extern "C" void kernel_launch(void* const* d_in, const int* in_sizes, int n_in,
                              void* d_out, int out_size, void* d_ws, size_t ws_size,
                              hipStream_t stream) {
    const float* x  = (const float*)d_in[0];
    const float* ea = (const float*)d_in[1];
    const int* ei    = (const int*)d_in[2];
    const int* batch = (const int*)d_in[3];
    auto ff = [&](int i) { return (const float*)d_in[i]; };
    const float *W1l = ff(4), *b1l = ff(5), *W1r = ff(6), *b1r = ff(7), *W1e = ff(8),
                *att1 = ff(9), *bias1 = ff(10);
    const float *W2l = ff(11), *b2l = ff(12), *W2r = ff(13), *b2r = ff(14), *W2e = ff(15),
                *att2 = ff(16), *bias2 = ff(17);
    const float *W3l = ff(18), *b3l = ff(19), *W3r = ff(20), *b3r = ff(21), *W3e = ff(22),
                *att3 = ff(23), *bias3 = ff(24);
    const float *G1w = ff(25), *G1b = ff(26), *G2w = ff(27), *G2b = ff(28), *Wreg = ff(29),
                *breg = ff(30);

    const int N = in_sizes[0] / 128;  // 40000
    const int E = in_sizes[2] / 2;    // 640000

    char* ws = (char*)d_ws;
    float*  bufA    = (float*)(ws);              // [N,128]
    float*  bufB    = (float*)(ws + 20480000);   // [N,128]
    float*  bufH    = (float*)(ws + 40960000);   // [N,128]
    int2*   elist   = (int2*)(ws + 61440000);    // [E] (src, edge_id)
    int*    row_ptr = (int*)(ws + 66560000);     // [N]
    int*    deg     = (int*)(ws + 66720000);     // [N]
    int*    cursor  = (int*)(ws + 66880000);     // [N]
    int*    excl    = (int*)(ws + 67040000);     // [N]
    int*    parts   = (int*)(ws + 67200000);     // [<=256]
    float*  gate    = (float*)(ws + 67204096);   // [N]
    float*  pooled  = (float*)(ws + 67364096);   // [64,64]
    float4* ea_s    = (float4*)(ws + 67380480);  // [E,32] floats, CSR-ordered (optional)
    const bool sorted_ea = ws_size >= (size_t)67380480 + (size_t)E * 32 * 4;

    auto cdiv = [](int a, int b) { return (a + b - 1) / b; };
    const int NB = cdiv(N, 256);
    const dim3 gemmG(N / 64, 2);
    const int AGGB = cdiv(N, 4);

    // ---- CSR build (once; graph shared by all 3 layers) ----
    k_fill<<<NB, 256, 0, stream>>>((unsigned*)deg, N, 0u);
    k_hist<<<cdiv(E, 256), 256, 0, stream>>>(ei, E, deg);
    k_scan_blocks<<<NB, 256, 0, stream>>>(deg, N, excl, parts);
    k_scan_parts<<<1, 256, 0, stream>>>(parts, NB);
    k_scan_add<<<NB, 256, 0, stream>>>(excl, parts, row_ptr, cursor, N);
    k_scatter<<<cdiv(E, 256), 256, 0, stream>>>(ei, E, cursor, elist);
    if (sorted_ea)
        k_reorder<<<cdiv(E * 8, 256), 256, 0, stream>>>(elist, ea, E, ea_s);

    // ---- layer 1 ----
    k_gemm2<128, 8><<<gemmG, 256, 0, stream>>>(x, W1l, b1l, W1r, b1r, bufA, bufB);
    if (sorted_ea)
        k_agg<2, true, true><<<AGGB, 256, 0, stream>>>(bufA, bufB, ea, ea_s, elist, row_ptr, deg, W1e, att1, bias1, bufH, N);
    else
        k_agg<2, true, false><<<AGGB, 256, 0, stream>>>(bufA, bufB, ea, ea_s, elist, row_ptr, deg, W1e, att1, bias1, bufH, N);

    // ---- layer 2 ----
    k_gemm2<128, 8><<<gemmG, 256, 0, stream>>>(bufH, W2l, b2l, W2r, b2r, bufA, bufB);
    if (sorted_ea)
        k_agg<2, true, true><<<AGGB, 256, 0, stream>>>(bufA, bufB, ea, ea_s, elist, row_ptr, deg, W2e, att2, bias2, bufH, N);
    else
        k_agg<2, true, false><<<AGGB, 256, 0, stream>>>(bufA, bufB, ea, ea_s, elist, row_ptr, deg, W2e, att2, bias2, bufH, N);

    // ---- layer 3 ----
    k_gemm2<64, 4><<<gemmG, 256, 0, stream>>>(bufH, W3l, b3l, W3r, b3r, bufA, bufB);
    if (sorted_ea)
        k_agg<1, false, true><<<AGGB, 256, 0, stream>>>(bufA, bufB, ea, ea_s, elist, row_ptr, deg, W3e, att3, bias3, bufH, N);
    else
        k_agg<1, false, false><<<AGGB, 256, 0, stream>>>(bufA, bufB, ea, ea_s, elist, row_ptr, deg, W3e, att3, bias3, bufH, N);

    // ---- attentional pooling + regressor ----
    k_gate<<<N / 64, 256, 0, stream>>>(bufH, G1w, G1b, G2w, G2b, gate, N);
    k_pool<<<64, 256, 0, stream>>>(bufH, gate, batch, pooled, N);
    k_final<<<1, 64, 0, stream>>>(pooled, Wreg, breg, (float*)d_out);
}

// Round 8
// 1912.036 us; speedup vs baseline: 1.1403x; 1.1403x over previous
//
#include <hip/hip_runtime.h>

__global__ void k_fill(unsigned* p, int n, unsigned v) {
    int i = blockIdx.x * blockDim.x + threadIdx.x;
    if (i < n) p[i] = v;
}

// ---------------- CSR build (graph identical across layers; built once) ----------------
__global__ void k_hist(const int* __restrict__ ei, int E, int* __restrict__ deg) {
    int e = blockIdx.x * blockDim.x + threadIdx.x;
    if (e < E) atomicAdd(&deg[ei[E + e]], 1);
}

__global__ void k_scan_blocks(const int* __restrict__ deg, int N,
                              int* __restrict__ excl, int* __restrict__ parts) {
    __shared__ int s[256];
    int t = threadIdx.x, i = blockIdx.x * 256 + t;
    int v = (i < N) ? deg[i] : 0;
    s[t] = v;
    __syncthreads();
    int acc = v;
    for (int off = 1; off < 256; off <<= 1) {
        int add = (t >= off) ? s[t - off] : 0;
        __syncthreads();
        acc += add;
        s[t] = acc;
        __syncthreads();
    }
    if (i < N) excl[i] = acc - v;
    if (t == 255) parts[blockIdx.x] = acc;
}

__global__ void k_scan_parts(int* __restrict__ parts, int nb) {
    __shared__ int s[256];
    int t = threadIdx.x;
    int v = (t < nb) ? parts[t] : 0;
    s[t] = v;
    __syncthreads();
    int acc = v;
    for (int off = 1; off < 256; off <<= 1) {
        int add = (t >= off) ? s[t - off] : 0;
        __syncthreads();
        acc += add;
        s[t] = acc;
        __syncthreads();
    }
    if (t < nb) parts[t] = acc - v;
}

__global__ void k_scan_add(const int* __restrict__ excl, const int* __restrict__ parts,
                           int* __restrict__ row_ptr, int* __restrict__ cursor, int N) {
    int i = blockIdx.x * blockDim.x + threadIdx.x;
    if (i >= N) return;
    int r = excl[i] + parts[i >> 8];
    row_ptr[i] = r;
    cursor[i] = r;
}

__global__ void k_scatter(const int* __restrict__ ei, int E, int* __restrict__ cursor,
                          int2* __restrict__ elist) {
    int e = blockIdx.x * blockDim.x + threadIdx.x;
    if (e >= E) return;
    int d = ei[E + e];
    int j = atomicAdd(&cursor[d], 1);
    elist[j] = make_int2(ei[e], e);
}

// permute edge_attr into CSR order: ea_s[j] = ea[elist[j].y]  (8 threads per edge)
__global__ void k_reorder(const int2* __restrict__ elist, const float* __restrict__ ea, int E,
                          float4* __restrict__ ea_s) {
    int idx = blockIdx.x * blockDim.x + threadIdx.x;
    int j = idx >> 3, q = idx & 7;
    if (j >= E) return;
    ea_s[(size_t)j * 8 + q] = ((const float4*)ea)[(size_t)elist[j].y * 8 + q];
}

// ---------------- Dual GEMM: out{l,r} = A @ W{l,r} + b{l,r} ----------------
template <int M, int RW>
__global__ __launch_bounds__(256) void k_gemm2(const float* __restrict__ A,
                                               const float* __restrict__ Wl, const float* __restrict__ bl,
                                               const float* __restrict__ Wr, const float* __restrict__ br,
                                               float* __restrict__ outl, float* __restrict__ outr) {
    constexpr int TX = M / 4;
    __shared__ float sA[32][68];
    __shared__ float sW[32][M];
    const float* W    = blockIdx.y ? Wr : Wl;
    const float* bias = blockIdx.y ? br : bl;
    float* out        = blockIdx.y ? outr : outl;
    int t = threadIdx.x;
    int tx = t % TX, ty = t / TX;
    int r0 = blockIdx.x * 64;
    float acc[RW][4] = {};
    for (int kt = 0; kt < 128; kt += 32) {
        for (int l = t; l < 512; l += 256) {
            int row = l >> 3, kq = (l & 7) << 2;
            float4 a = *(const float4*)&A[(size_t)(r0 + row) * 128 + kt + kq];
            sA[kq + 0][row] = a.x; sA[kq + 1][row] = a.y;
            sA[kq + 2][row] = a.z; sA[kq + 3][row] = a.w;
        }
        for (int l = t; l < 32 * M / 4; l += 256) {
            int kk = (l * 4) / M, cc = (l * 4) % M;
            *(float4*)&sW[kk][cc] = *(const float4*)&W[(size_t)(kt + kk) * M + cc];
        }
        __syncthreads();
#pragma unroll
        for (int k = 0; k < 32; k++) {
            float4 w = *(float4*)&sW[k][tx * 4];
            float ar[RW];
#pragma unroll
            for (int i = 0; i < RW; i += 4) {
                float4 a = *(float4*)&sA[k][ty * RW + i];
                ar[i] = a.x; ar[i + 1] = a.y; ar[i + 2] = a.z; ar[i + 3] = a.w;
            }
#pragma unroll
            for (int i = 0; i < RW; i++) {
                acc[i][0] += ar[i] * w.x; acc[i][1] += ar[i] * w.y;
                acc[i][2] += ar[i] * w.z; acc[i][3] += ar[i] * w.w;
            }
        }
        __syncthreads();
    }
    float4 b = *(const float4*)&bias[tx * 4];
#pragma unroll
    for (int i = 0; i < RW; i++) {
        float4 v;
        v.x = acc[i][0] + b.x; v.y = acc[i][1] + b.y;
        v.z = acc[i][2] + b.z; v.w = acc[i][3] + b.w;
        *(float4*)&out[(size_t)(r0 + ty * RW + i) * M + tx * 4] = v;
    }
}

// ---------------- Fused per-dst GATv2 aggregation (CSR, zero atomics) ----------------
// Round-5 structure (wave per node, ea loads shared across heads) + 2-edge unroll with
// NAMED SCALARS ONLY (round-7's indexed arrays spilled to scratch: 2.5 GB HBM traffic).
// The 2x unroll gives 2 (H=1) / 4 (H=2) independent butterfly chains interleaved and
// 2-deep gather pipelining. No extra launch_bounds: let the allocator pick occupancy.
template <int H, bool RELU, bool SORTED>
__global__ __launch_bounds__(256) void k_agg(const float* __restrict__ xl, const float* __restrict__ xr,
                                             const float* __restrict__ ea, const float4* __restrict__ ea_s,
                                             const int2* __restrict__ elist,
                                             const int* __restrict__ row_ptr, const int* __restrict__ deg,
                                             const float* __restrict__ We, const float* __restrict__ att,
                                             const float* __restrict__ bias, float* __restrict__ out, int N) {
    constexpr int HC = H * 64;
    int tid = threadIdx.x, wv = tid >> 6, lane = tid & 63;
    float rWe0[32], rWe1[H == 2 ? 32 : 1];
#pragma unroll
    for (int k = 0; k < 32; k++) rWe0[k] = We[k * HC + lane];
    if constexpr (H == 2) {
#pragma unroll
        for (int k = 0; k < 32; k++) rWe1[k] = We[k * HC + 64 + lane];
    }
    float att0 = att[lane], b0 = bias[lane];
    float att1 = 0.f, b1 = 0.f;
    if constexpr (H == 2) { att1 = att[64 + lane]; b1 = bias[64 + lane]; }
    int n = blockIdx.x * 4 + wv;
    if (n >= N) return;
    int start = row_ptr[n], d = deg[n];
    float xr0 = xr[(size_t)n * HC + lane];
    float xr1 = (H == 2) ? xr[(size_t)n * HC + 64 + lane] : 0.f;
    float acc0 = 0.f, acc1 = 0.f, den0 = 0.f, den1 = 0.f;
    int j = 0;
    for (; j + 2 <= d; j += 2) {
        int2 spA = elist[start + j];
        int2 spB = elist[start + j + 1];
        const float4* eapA = SORTED ? (ea_s + (size_t)(start + j) * 8)
                                    : (const float4*)(ea + (size_t)spA.y * 32);
        const float4* eapB = SORTED ? (ea_s + (size_t)(start + j + 1) * 8)
                                    : (const float4*)(ea + (size_t)spB.y * 32);
        const float* xlsA = xl + (size_t)spA.x * HC;
        const float* xlsB = xl + (size_t)spB.x * HC;
        float xlA0 = xlsA[lane];
        float xlB0 = xlsB[lane];
        float xlA1 = 0.f, xlB1 = 0.f;
        if constexpr (H == 2) { xlA1 = xlsA[64 + lane]; xlB1 = xlsB[64 + lane]; }
        float eeA0 = 0.f, eeA1 = 0.f, eeB0 = 0.f, eeB1 = 0.f;
#pragma unroll
        for (int kq = 0; kq < 8; kq++) {
            float4 va = eapA[kq];
            float4 vb = eapB[kq];
            eeA0 = fmaf(va.x, rWe0[kq * 4 + 0], eeA0);
            eeA0 = fmaf(va.y, rWe0[kq * 4 + 1], eeA0);
            eeA0 = fmaf(va.z, rWe0[kq * 4 + 2], eeA0);
            eeA0 = fmaf(va.w, rWe0[kq * 4 + 3], eeA0);
            eeB0 = fmaf(vb.x, rWe0[kq * 4 + 0], eeB0);
            eeB0 = fmaf(vb.y, rWe0[kq * 4 + 1], eeB0);
            eeB0 = fmaf(vb.z, rWe0[kq * 4 + 2], eeB0);
            eeB0 = fmaf(vb.w, rWe0[kq * 4 + 3], eeB0);
            if constexpr (H == 2) {
                eeA1 = fmaf(va.x, rWe1[kq * 4 + 0], eeA1);
                eeA1 = fmaf(va.y, rWe1[kq * 4 + 1], eeA1);
                eeA1 = fmaf(va.z, rWe1[kq * 4 + 2], eeA1);
                eeA1 = fmaf(va.w, rWe1[kq * 4 + 3], eeA1);
                eeB1 = fmaf(vb.x, rWe1[kq * 4 + 0], eeB1);
                eeB1 = fmaf(vb.y, rWe1[kq * 4 + 1], eeB1);
                eeB1 = fmaf(vb.z, rWe1[kq * 4 + 2], eeB1);
                eeB1 = fmaf(vb.w, rWe1[kq * 4 + 3], eeB1);
            }
        }
        float vA0 = xlA0 + xr0 + eeA0;
        vA0 = vA0 > 0.f ? vA0 : 0.2f * vA0;
        float vB0 = xlB0 + xr0 + eeB0;
        vB0 = vB0 > 0.f ? vB0 : 0.2f * vB0;
        float pA0 = att0 * vA0;
        float pB0 = att0 * vB0;
        float pA1 = 0.f, pB1 = 0.f;
        if constexpr (H == 2) {
            float vA1 = xlA1 + xr1 + eeA1;
            vA1 = vA1 > 0.f ? vA1 : 0.2f * vA1;
            float vB1 = xlB1 + xr1 + eeB1;
            vB1 = vB1 > 0.f ? vB1 : 0.2f * vB1;
            pA1 = att1 * vA1;
            pB1 = att1 * vB1;
        }
#pragma unroll
        for (int m = 32; m; m >>= 1) {
            pA0 += __shfl_xor(pA0, m);
            pB0 += __shfl_xor(pB0, m);
            if constexpr (H == 2) {
                pA1 += __shfl_xor(pA1, m);
                pB1 += __shfl_xor(pB1, m);
            }
        }
        float exA0 = __expf(pA0);
        float exB0 = __expf(pB0);
        acc0 = fmaf(exA0, xlA0, acc0); den0 += exA0;
        acc0 = fmaf(exB0, xlB0, acc0); den0 += exB0;
        if constexpr (H == 2) {
            float exA1 = __expf(pA1);
            float exB1 = __expf(pB1);
            acc1 = fmaf(exA1, xlA1, acc1); den1 += exA1;
            acc1 = fmaf(exB1, xlB1, acc1); den1 += exB1;
        }
    }
    if (j < d) {  // remainder (d odd)
        int2 sp = elist[start + j];
        const float4* eap = SORTED ? (ea_s + (size_t)(start + j) * 8)
                                   : (const float4*)(ea + (size_t)sp.y * 32);
        const float* xls = xl + (size_t)sp.x * HC;
        float xlA = xls[lane];
        float xlB = (H == 2) ? xls[64 + lane] : 0.f;
        float ee0 = 0.f, ee1 = 0.f;
#pragma unroll
        for (int kq = 0; kq < 8; kq++) {
            float4 v = eap[kq];
            ee0 = fmaf(v.x, rWe0[kq * 4 + 0], ee0);
            ee0 = fmaf(v.y, rWe0[kq * 4 + 1], ee0);
            ee0 = fmaf(v.z, rWe0[kq * 4 + 2], ee0);
            ee0 = fmaf(v.w, rWe0[kq * 4 + 3], ee0);
            if constexpr (H == 2) {
                ee1 = fmaf(v.x, rWe1[kq * 4 + 0], ee1);
                ee1 = fmaf(v.y, rWe1[kq * 4 + 1], ee1);
                ee1 = fmaf(v.z, rWe1[kq * 4 + 2], ee1);
                ee1 = fmaf(v.w, rWe1[kq * 4 + 3], ee1);
            }
        }
        float v0 = xlA + xr0 + ee0;
        v0 = v0 > 0.f ? v0 : 0.2f * v0;
        float p0 = att0 * v0, p1 = 0.f;
        if constexpr (H == 2) {
            float v1 = xlB + xr1 + ee1;
            v1 = v1 > 0.f ? v1 : 0.2f * v1;
            p1 = att1 * v1;
        }
#pragma unroll
        for (int m = 32; m; m >>= 1) {
            p0 += __shfl_xor(p0, m);
            if constexpr (H == 2) p1 += __shfl_xor(p1, m);
        }
        float ex0 = __expf(p0);
        acc0 = fmaf(ex0, xlA, acc0); den0 += ex0;
        if constexpr (H == 2) {
            float ex1 = __expf(p1);
            acc1 = fmaf(ex1, xlB, acc1); den1 += ex1;
        }
    }
    float o0 = acc0 / (den0 + 1e-16f) + b0;
    if (RELU) o0 = o0 > 0.f ? o0 : 0.f;
    out[(size_t)n * HC + lane] = o0;
    if constexpr (H == 2) {
        float o1 = acc1 / (den1 + 1e-16f) + b1;
        if (RELU) o1 = o1 > 0.f ? o1 : 0.f;
        out[(size_t)n * HC + 64 + lane] = o1;
    }
}

// ---------------- gate MLP: gate[n] = exp(relu(h[n]@G1w+G1b)@G2w + G2b) ----------------
__global__ __launch_bounds__(256) void k_gate(const float* __restrict__ h, const float* __restrict__ G1w,
                                              const float* __restrict__ G1b, const float* __restrict__ G2w,
                                              const float* __restrict__ G2b,
                                              float* __restrict__ gate, int N) {
    __shared__ float sH[64][64];
    __shared__ float part[64][2];
    int t = threadIdx.x;
    int n0 = blockIdx.x * 64;
    for (int l = t; l < 1024; l += 256) {
        float4 v = ((const float4*)(h + (size_t)n0 * 64))[l];
        int n = l >> 4, kq = (l & 15) << 2;
        *(float4*)&sH[n][kq] = v;
    }
    int c = t & 127, half = t >> 7;
    float rW[64];
#pragma unroll
    for (int k = 0; k < 64; k++) rW[k] = G1w[k * 128 + c];
    float g1b = G1b[c], g2w = G2w[c];
    __syncthreads();
    for (int nn = 0; nn < 32; nn++) {
        int n = half * 32 + nn;
        float acc = g1b;
#pragma unroll
        for (int k = 0; k < 64; k += 4) {
            float4 hv = *(const float4*)&sH[n][k];
            acc = fmaf(hv.x, rW[k], acc);
            acc = fmaf(hv.y, rW[k + 1], acc);
            acc = fmaf(hv.z, rW[k + 2], acc);
            acc = fmaf(hv.w, rW[k + 3], acc);
        }
        acc = acc > 0.f ? acc : 0.f;
        float p = acc * g2w;
#pragma unroll
        for (int m = 32; m; m >>= 1) p += __shfl_xor(p, m);
        if ((t & 63) == 0) part[n][(t >> 6) & 1] = p;
    }
    __syncthreads();
    if (t < 64) gate[n0 + t] = __expf(part[t][0] + part[t][1] + G2b[0]);
}

// ---------------- pooling: one block per graph (batch sorted -> binary search range) ----------------
__global__ __launch_bounds__(256) void k_pool(const float* __restrict__ h, const float* __restrict__ gate,
                                              const int* __restrict__ batch,
                                              float* __restrict__ pooled, int N) {
    int g = blockIdx.x;
    int lo = 0, hi = N;
    while (lo < hi) { int mid = (lo + hi) >> 1; if (batch[mid] < g) lo = mid + 1; else hi = mid; }
    int start = lo;
    lo = 0; hi = N;
    while (lo < hi) { int mid = (lo + hi) >> 1; if (batch[mid] < g + 1) lo = mid + 1; else hi = mid; }
    int end = lo;
    int t = threadIdx.x, wv = t >> 6, lane = t & 63;
    float acc = 0.f, den = 0.f;
    for (int n = start + wv; n < end; n += 4) {
        float gv = gate[n];
        acc = fmaf(gv, h[(size_t)n * 64 + lane], acc);
        den += gv;
    }
    __shared__ float sacc[4][64];
    __shared__ float sden[4];
    sacc[wv][lane] = acc;
    if (lane == 0) sden[wv] = den;
    __syncthreads();
    if (wv == 0) {
        float a = sacc[0][lane] + sacc[1][lane] + sacc[2][lane] + sacc[3][lane];
        float d = sden[0] + sden[1] + sden[2] + sden[3] + 1e-16f;
        pooled[g * 64 + lane] = a / d;
    }
}

__global__ void k_final(const float* __restrict__ pooled, const float* __restrict__ Wreg,
                        const float* __restrict__ breg, float* __restrict__ out) {
    int g = threadIdx.x;
    float acc = breg[0];
    for (int c = 0; c < 64; c++) acc += pooled[g * 64 + c] * Wreg[c];
    out[g] = acc;
}

extern "C" void kernel_launch(void* const* d_in, const int* in_sizes, int n_in,
                              void* d_out, int out_size, void* d_ws, size_t ws_size,
                              hipStream_t stream) {
    const float* x  = (const float*)d_in[0];
    const float* ea = (const float*)d_in[1];
    const int* ei    = (const int*)d_in[2];
    const int* batch = (const int*)d_in[3];
    auto ff = [&](int i) { return (const float*)d_in[i]; };
    const float *W1l = ff(4), *b1l = ff(5), *W1r = ff(6), *b1r = ff(7), *W1e = ff(8),
                *att1 = ff(9), *bias1 = ff(10);
    const float *W2l = ff(11), *b2l = ff(12), *W2r = ff(13), *b2r = ff(14), *W2e = ff(15),
                *att2 = ff(16), *bias2 = ff(17);
    const float *W3l = ff(18), *b3l = ff(19), *W3r = ff(20), *b3r = ff(21), *W3e = ff(22),
                *att3 = ff(23), *bias3 = ff(24);
    const float *G1w = ff(25), *G1b = ff(26), *G2w = ff(27), *G2b = ff(28), *Wreg = ff(29),
                *breg = ff(30);

    const int N = in_sizes[0] / 128;  // 40000
    const int E = in_sizes[2] / 2;    // 640000

    char* ws = (char*)d_ws;
    float*  bufA    = (float*)(ws);              // [N,128]
    float*  bufB    = (float*)(ws + 20480000);   // [N,128]
    float*  bufH    = (float*)(ws + 40960000);   // [N,128]
    int2*   elist   = (int2*)(ws + 61440000);    // [E] (src, edge_id)
    int*    row_ptr = (int*)(ws + 66560000);     // [N]
    int*    deg     = (int*)(ws + 66720000);     // [N]
    int*    cursor  = (int*)(ws + 66880000);     // [N]
    int*    excl    = (int*)(ws + 67040000);     // [N]
    int*    parts   = (int*)(ws + 67200000);     // [<=256]
    float*  gate    = (float*)(ws + 67204096);   // [N]
    float*  pooled  = (float*)(ws + 67364096);   // [64,64]
    float4* ea_s    = (float4*)(ws + 67380480);  // [E,32] floats, CSR-ordered (optional)
    const bool sorted_ea = ws_size >= (size_t)67380480 + (size_t)E * 32 * 4;

    auto cdiv = [](int a, int b) { return (a + b - 1) / b; };
    const int NB = cdiv(N, 256);
    const dim3 gemmG(N / 64, 2);
    const int AGGB = cdiv(N, 4);

    // ---- CSR build (once; graph shared by all 3 layers) ----
    k_fill<<<NB, 256, 0, stream>>>((unsigned*)deg, N, 0u);
    k_hist<<<cdiv(E, 256), 256, 0, stream>>>(ei, E, deg);
    k_scan_blocks<<<NB, 256, 0, stream>>>(deg, N, excl, parts);
    k_scan_parts<<<1, 256, 0, stream>>>(parts, NB);
    k_scan_add<<<NB, 256, 0, stream>>>(excl, parts, row_ptr, cursor, N);
    k_scatter<<<cdiv(E, 256), 256, 0, stream>>>(ei, E, cursor, elist);
    if (sorted_ea)
        k_reorder<<<cdiv(E * 8, 256), 256, 0, stream>>>(elist, ea, E, ea_s);

    // ---- layer 1 ----
    k_gemm2<128, 8><<<gemmG, 256, 0, stream>>>(x, W1l, b1l, W1r, b1r, bufA, bufB);
    if (sorted_ea)
        k_agg<2, true, true><<<AGGB, 256, 0, stream>>>(bufA, bufB, ea, ea_s, elist, row_ptr, deg, W1e, att1, bias1, bufH, N);
    else
        k_agg<2, true, false><<<AGGB, 256, 0, stream>>>(bufA, bufB, ea, ea_s, elist, row_ptr, deg, W1e, att1, bias1, bufH, N);

    // ---- layer 2 ----
    k_gemm2<128, 8><<<gemmG, 256, 0, stream>>>(bufH, W2l, b2l, W2r, b2r, bufA, bufB);
    if (sorted_ea)
        k_agg<2, true, true><<<AGGB, 256, 0, stream>>>(bufA, bufB, ea, ea_s, elist, row_ptr, deg, W2e, att2, bias2, bufH, N);
    else
        k_agg<2, true, false><<<AGGB, 256, 0, stream>>>(bufA, bufB, ea, ea_s, elist, row_ptr, deg, W2e, att2, bias2, bufH, N);

    // ---- layer 3 ----
    k_gemm2<64, 4><<<gemmG, 256, 0, stream>>>(bufH, W3l, b3l, W3r, b3r, bufA, bufB);
    if (sorted_ea)
        k_agg<1, false, true><<<AGGB, 256, 0, stream>>>(bufA, bufB, ea, ea_s, elist, row_ptr, deg, W3e, att3, bias3, bufH, N);
    else
        k_agg<1, false, false><<<AGGB, 256, 0, stream>>>(bufA, bufB, ea, ea_s, elist, row_ptr, deg, W3e, att3, bias3, bufH, N);

    // ---- attentional pooling + regressor ----
    k_gate<<<N / 64, 256, 0, stream>>>(bufH, G1w, G1b, G2w, G2b, gate, N);
    k_pool<<<64, 256, 0, stream>>>(bufH, gate, batch, pooled, N);
    k_final<<<1, 64, 0, stream>>>(pooled, Wreg, breg, (float*)d_out);
}

// Round 9
// 1614.093 us; speedup vs baseline: 1.3508x; 1.1846x over previous
//
#include <hip/hip_runtime.h>

__global__ void k_fill(unsigned* p, int n, unsigned v) {
    int i = blockIdx.x * blockDim.x + threadIdx.x;
    if (i < n) p[i] = v;
}

// ---------------- CSR build (graph identical across layers; built once) ----------------
__global__ void k_hist(const int* __restrict__ ei, int E, int* __restrict__ deg) {
    int e = blockIdx.x * blockDim.x + threadIdx.x;
    if (e < E) atomicAdd(&deg[ei[E + e]], 1);
}

__global__ void k_scan_blocks(const int* __restrict__ deg, int N,
                              int* __restrict__ excl, int* __restrict__ parts) {
    __shared__ int s[256];
    int t = threadIdx.x, i = blockIdx.x * 256 + t;
    int v = (i < N) ? deg[i] : 0;
    s[t] = v;
    __syncthreads();
    int acc = v;
    for (int off = 1; off < 256; off <<= 1) {
        int add = (t >= off) ? s[t - off] : 0;
        __syncthreads();
        acc += add;
        s[t] = acc;
        __syncthreads();
    }
    if (i < N) excl[i] = acc - v;
    if (t == 255) parts[blockIdx.x] = acc;
}

__global__ void k_scan_parts(int* __restrict__ parts, int nb) {
    __shared__ int s[256];
    int t = threadIdx.x;
    int v = (t < nb) ? parts[t] : 0;
    s[t] = v;
    __syncthreads();
    int acc = v;
    for (int off = 1; off < 256; off <<= 1) {
        int add = (t >= off) ? s[t - off] : 0;
        __syncthreads();
        acc += add;
        s[t] = acc;
        __syncthreads();
    }
    if (t < nb) parts[t] = acc - v;
}

__global__ void k_scan_add(const int* __restrict__ excl, const int* __restrict__ parts,
                           int* __restrict__ row_ptr, int* __restrict__ cursor, int N) {
    int i = blockIdx.x * blockDim.x + threadIdx.x;
    if (i >= N) return;
    int r = excl[i] + parts[i >> 8];
    row_ptr[i] = r;
    cursor[i] = r;
}

__global__ void k_scatter(const int* __restrict__ ei, int E, int* __restrict__ cursor,
                          int2* __restrict__ elist) {
    int e = blockIdx.x * blockDim.x + threadIdx.x;
    if (e >= E) return;
    int d = ei[E + e];
    int j = atomicAdd(&cursor[d], 1);
    elist[j] = make_int2(ei[e], e);
}

// permute edge_attr into CSR order: ea_s[j] = ea[elist[j].y]  (8 threads per edge)
__global__ void k_reorder(const int2* __restrict__ elist, const float* __restrict__ ea, int E,
                          float4* __restrict__ ea_s) {
    int idx = blockIdx.x * blockDim.x + threadIdx.x;
    int j = idx >> 3, q = idx & 7;
    if (j >= E) return;
    ea_s[(size_t)j * 8 + q] = ((const float4*)ea)[(size_t)elist[j].y * 8 + q];
}

// ---------------- Dual GEMM: out{l,r} = A @ W{l,r} + b{l,r} ----------------
template <int M, int RW>
__global__ __launch_bounds__(256) void k_gemm2(const float* __restrict__ A,
                                               const float* __restrict__ Wl, const float* __restrict__ bl,
                                               const float* __restrict__ Wr, const float* __restrict__ br,
                                               float* __restrict__ outl, float* __restrict__ outr) {
    constexpr int TX = M / 4;
    __shared__ float sA[32][68];
    __shared__ float sW[32][M];
    const float* W    = blockIdx.y ? Wr : Wl;
    const float* bias = blockIdx.y ? br : bl;
    float* out        = blockIdx.y ? outr : outl;
    int t = threadIdx.x;
    int tx = t % TX, ty = t / TX;
    int r0 = blockIdx.x * 64;
    float acc[RW][4] = {};
    for (int kt = 0; kt < 128; kt += 32) {
        for (int l = t; l < 512; l += 256) {
            int row = l >> 3, kq = (l & 7) << 2;
            float4 a = *(const float4*)&A[(size_t)(r0 + row) * 128 + kt + kq];
            sA[kq + 0][row] = a.x; sA[kq + 1][row] = a.y;
            sA[kq + 2][row] = a.z; sA[kq + 3][row] = a.w;
        }
        for (int l = t; l < 32 * M / 4; l += 256) {
            int kk = (l * 4) / M, cc = (l * 4) % M;
            *(float4*)&sW[kk][cc] = *(const float4*)&W[(size_t)(kt + kk) * M + cc];
        }
        __syncthreads();
#pragma unroll
        for (int k = 0; k < 32; k++) {
            float4 w = *(float4*)&sW[k][tx * 4];
            float ar[RW];
#pragma unroll
            for (int i = 0; i < RW; i += 4) {
                float4 a = *(float4*)&sA[k][ty * RW + i];
                ar[i] = a.x; ar[i + 1] = a.y; ar[i + 2] = a.z; ar[i + 3] = a.w;
            }
#pragma unroll
            for (int i = 0; i < RW; i++) {
                acc[i][0] += ar[i] * w.x; acc[i][1] += ar[i] * w.y;
                acc[i][2] += ar[i] * w.z; acc[i][3] += ar[i] * w.w;
            }
        }
        __syncthreads();
    }
    float4 b = *(const float4*)&bias[tx * 4];
#pragma unroll
    for (int i = 0; i < RW; i++) {
        float4 v;
        v.x = acc[i][0] + b.x; v.y = acc[i][1] + b.y;
        v.z = acc[i][2] + b.z; v.w = acc[i][3] + b.w;
        *(float4*)&out[(size_t)(r0 + ty * RW + i) * M + tx * 4] = v;
    }
}

// ---------------- Fused per-dst GATv2 aggregation, H=2 (CSR, zero atomics) ----------------
// Half-wave head split: lanes 0-31 = head 0 (cols s, s+32), lanes 32-63 = head 1.
// Per edge: each lane folds its 2 cols locally -> ONE 5-step butterfly within the half
// (was 2 heads x 6 steps full-wave), ONE exp. Registers/loads identical to round-5 (64 VGPR).
template <bool RELU, bool SORTED>
__global__ __launch_bounds__(256) void k_agg2(const float* __restrict__ xl, const float* __restrict__ xr,
                                              const float* __restrict__ ea, const float4* __restrict__ ea_s,
                                              const int2* __restrict__ elist,
                                              const int* __restrict__ row_ptr, const int* __restrict__ deg,
                                              const float* __restrict__ We, const float* __restrict__ att,
                                              const float* __restrict__ bias, float* __restrict__ out, int N) {
    int tid = threadIdx.x, wv = tid >> 6, lane = tid & 63;
    int half = lane >> 5, s = lane & 31;
    int c0 = half * 64 + s;    // head = half owns cols c0 and c0+32
    int c1 = c0 + 32;
    float rWeA[32], rWeB[32];
#pragma unroll
    for (int k = 0; k < 32; k++) rWeA[k] = We[k * 128 + c0];
#pragma unroll
    for (int k = 0; k < 32; k++) rWeB[k] = We[k * 128 + c1];
    float attA = att[c0], attB = att[c1], bA = bias[c0], bB = bias[c1];
    int n = blockIdx.x * 4 + wv;
    if (n >= N) return;
    int start = row_ptr[n], d = deg[n];
    float xrA = xr[(size_t)n * 128 + c0];
    float xrB = xr[(size_t)n * 128 + c1];
    float accA = 0.f, accB = 0.f, den = 0.f;
    for (int j = 0; j < d; j++) {
        int2 sp = elist[start + j];
        const float4* eap = SORTED ? (ea_s + (size_t)(start + j) * 8)
                                   : (const float4*)(ea + (size_t)sp.y * 32);
        const float* xls = xl + (size_t)sp.x * 128;
        float xlA = xls[c0];
        float xlB = xls[c1];
        float eeA = 0.f, eeB = 0.f;
#pragma unroll
        for (int kq = 0; kq < 8; kq++) {
            float4 v = eap[kq];
            eeA = fmaf(v.x, rWeA[kq * 4 + 0], eeA);
            eeA = fmaf(v.y, rWeA[kq * 4 + 1], eeA);
            eeA = fmaf(v.z, rWeA[kq * 4 + 2], eeA);
            eeA = fmaf(v.w, rWeA[kq * 4 + 3], eeA);
            eeB = fmaf(v.x, rWeB[kq * 4 + 0], eeB);
            eeB = fmaf(v.y, rWeB[kq * 4 + 1], eeB);
            eeB = fmaf(v.z, rWeB[kq * 4 + 2], eeB);
            eeB = fmaf(v.w, rWeB[kq * 4 + 3], eeB);
        }
        float vA = xlA + xrA + eeA;
        vA = vA > 0.f ? vA : 0.2f * vA;
        float vB = xlB + xrB + eeB;
        vB = vB > 0.f ? vB : 0.2f * vB;
        float p = fmaf(attA, vA, attB * vB);
#pragma unroll
        for (int m = 1; m <= 16; m <<= 1) p += __shfl_xor(p, m);   // reduce within 32-lane half
        float ex = __expf(p);
        accA = fmaf(ex, xlA, accA);
        accB = fmaf(ex, xlB, accB);
        den += ex;
    }
    float inv = 1.f / (den + 1e-16f);
    float oA = fmaf(accA, inv, bA);
    float oB = fmaf(accB, inv, bB);
    if (RELU) { oA = oA > 0.f ? oA : 0.f; oB = oB > 0.f ? oB : 0.f; }
    out[(size_t)n * 128 + c0] = oA;
    out[(size_t)n * 128 + c1] = oB;
}

// ---------------- Fused per-dst GATv2 aggregation, H=1 (CSR, zero atomics) ----------------
// Half-wave EDGE split: lanes 0-31 process edge j, lanes 32-63 edge j+1 (2 cols/lane).
// Edge loop halves; 5-step butterfly per half; 3 cross-half shuffles once per node.
template <bool SORTED>
__global__ __launch_bounds__(256) void k_agg1(const float* __restrict__ xl, const float* __restrict__ xr,
                                              const float* __restrict__ ea, const float4* __restrict__ ea_s,
                                              const int2* __restrict__ elist,
                                              const int* __restrict__ row_ptr, const int* __restrict__ deg,
                                              const float* __restrict__ We, const float* __restrict__ att,
                                              const float* __restrict__ bias, float* __restrict__ out, int N) {
    int tid = threadIdx.x, wv = tid >> 6, lane = tid & 63;
    int half = lane >> 5, s = lane & 31;
    int c0 = s, c1 = s + 32;
    float rWeA[32], rWeB[32];
#pragma unroll
    for (int k = 0; k < 32; k++) rWeA[k] = We[k * 64 + c0];
#pragma unroll
    for (int k = 0; k < 32; k++) rWeB[k] = We[k * 64 + c1];
    float attA = att[c0], attB = att[c1], bA = bias[c0], bB = bias[c1];
    int n = blockIdx.x * 4 + wv;
    if (n >= N) return;
    int start = row_ptr[n], d = deg[n];
    float xrA = xr[(size_t)n * 64 + c0];
    float xrB = xr[(size_t)n * 64 + c1];
    float accA = 0.f, accB = 0.f, den = 0.f;
    for (int j = 0; j < d; j += 2) {
        int jj = j + half;
        bool valid = jj < d;
        int idx = start + (valid ? jj : d - 1);
        int2 sp = elist[idx];
        const float4* eap = SORTED ? (ea_s + (size_t)idx * 8)
                                   : (const float4*)(ea + (size_t)sp.y * 32);
        const float* xls = xl + (size_t)sp.x * 64;
        float xlA = xls[c0];
        float xlB = xls[c1];
        float eeA = 0.f, eeB = 0.f;
#pragma unroll
        for (int kq = 0; kq < 8; kq++) {
            float4 v = eap[kq];
            eeA = fmaf(v.x, rWeA[kq * 4 + 0], eeA);
            eeA = fmaf(v.y, rWeA[kq * 4 + 1], eeA);
            eeA = fmaf(v.z, rWeA[kq * 4 + 2], eeA);
            eeA = fmaf(v.w, rWeA[kq * 4 + 3], eeA);
            eeB = fmaf(v.x, rWeB[kq * 4 + 0], eeB);
            eeB = fmaf(v.y, rWeB[kq * 4 + 1], eeB);
            eeB = fmaf(v.z, rWeB[kq * 4 + 2], eeB);
            eeB = fmaf(v.w, rWeB[kq * 4 + 3], eeB);
        }
        float vA = xlA + xrA + eeA;
        vA = vA > 0.f ? vA : 0.2f * vA;
        float vB = xlB + xrB + eeB;
        vB = vB > 0.f ? vB : 0.2f * vB;
        float p = fmaf(attA, vA, attB * vB);
#pragma unroll
        for (int m = 1; m <= 16; m <<= 1) p += __shfl_xor(p, m);   // reduce within 32-lane half
        float ex = valid ? __expf(p) : 0.f;
        accA = fmaf(ex, xlA, accA);
        accB = fmaf(ex, xlB, accB);
        den += ex;
    }
    // combine the two half-wave accumulators
    accA += __shfl_xor(accA, 32);
    accB += __shfl_xor(accB, 32);
    den  += __shfl_xor(den, 32);
    float inv = 1.f / (den + 1e-16f);
    float oA = fmaf(accA, inv, bA);
    float oB = fmaf(accB, inv, bB);
    if (half == 0) {
        out[(size_t)n * 64 + c0] = oA;
        out[(size_t)n * 64 + c1] = oB;
    }
}

// ---------------- gate MLP: gate[n] = exp(relu(h[n]@G1w+G1b)@G2w + G2b) ----------------
__global__ __launch_bounds__(256) void k_gate(const float* __restrict__ h, const float* __restrict__ G1w,
                                              const float* __restrict__ G1b, const float* __restrict__ G2w,
                                              const float* __restrict__ G2b,
                                              float* __restrict__ gate, int N) {
    __shared__ float sH[64][64];
    __shared__ float part[64][2];
    int t = threadIdx.x;
    int n0 = blockIdx.x * 64;
    for (int l = t; l < 1024; l += 256) {
        float4 v = ((const float4*)(h + (size_t)n0 * 64))[l];
        int n = l >> 4, kq = (l & 15) << 2;
        *(float4*)&sH[n][kq] = v;
    }
    int c = t & 127, half = t >> 7;
    float rW[64];
#pragma unroll
    for (int k = 0; k < 64; k++) rW[k] = G1w[k * 128 + c];
    float g1b = G1b[c], g2w = G2w[c];
    __syncthreads();
    for (int nn = 0; nn < 32; nn++) {
        int n = half * 32 + nn;
        float acc = g1b;
#pragma unroll
        for (int k = 0; k < 64; k += 4) {
            float4 hv = *(const float4*)&sH[n][k];
            acc = fmaf(hv.x, rW[k], acc);
            acc = fmaf(hv.y, rW[k + 1], acc);
            acc = fmaf(hv.z, rW[k + 2], acc);
            acc = fmaf(hv.w, rW[k + 3], acc);
        }
        acc = acc > 0.f ? acc : 0.f;
        float p = acc * g2w;
#pragma unroll
        for (int m = 32; m; m >>= 1) p += __shfl_xor(p, m);
        if ((t & 63) == 0) part[n][(t >> 6) & 1] = p;
    }
    __syncthreads();
    if (t < 64) gate[n0 + t] = __expf(part[t][0] + part[t][1] + G2b[0]);
}

// ---------------- pooling: one block per graph (batch sorted -> binary search range) ----------------
__global__ __launch_bounds__(256) void k_pool(const float* __restrict__ h, const float* __restrict__ gate,
                                              const int* __restrict__ batch,
                                              float* __restrict__ pooled, int N) {
    int g = blockIdx.x;
    int lo = 0, hi = N;
    while (lo < hi) { int mid = (lo + hi) >> 1; if (batch[mid] < g) lo = mid + 1; else hi = mid; }
    int start = lo;
    lo = 0; hi = N;
    while (lo < hi) { int mid = (lo + hi) >> 1; if (batch[mid] < g + 1) lo = mid + 1; else hi = mid; }
    int end = lo;
    int t = threadIdx.x, wv = t >> 6, lane = t & 63;
    float acc = 0.f, den = 0.f;
    for (int n = start + wv; n < end; n += 4) {
        float gv = gate[n];
        acc = fmaf(gv, h[(size_t)n * 64 + lane], acc);
        den += gv;
    }
    __shared__ float sacc[4][64];
    __shared__ float sden[4];
    sacc[wv][lane] = acc;
    if (lane == 0) sden[wv] = den;
    __syncthreads();
    if (wv == 0) {
        float a = sacc[0][lane] + sacc[1][lane] + sacc[2][lane] + sacc[3][lane];
        float d = sden[0] + sden[1] + sden[2] + sden[3] + 1e-16f;
        pooled[g * 64 + lane] = a / d;
    }
}

__global__ void k_final(const float* __restrict__ pooled, const float* __restrict__ Wreg,
                        const float* __restrict__ breg, float* __restrict__ out) {
    int g = threadIdx.x;
    float acc = breg[0];
    for (int c = 0; c < 64; c++) acc += pooled[g * 64 + c] * Wreg[c];
    out[g] = acc;
}

extern "C" void kernel_launch(void* const* d_in, const int* in_sizes, int n_in,
                              void* d_out, int out_size, void* d_ws, size_t ws_size,
                              hipStream_t stream) {
    const float* x  = (const float*)d_in[0];
    const float* ea = (const float*)d_in[1];
    const int* ei    = (const int*)d_in[2];
    const int* batch = (const int*)d_in[3];
    auto ff = [&](int i) { return (const float*)d_in[i]; };
    const float *W1l = ff(4), *b1l = ff(5), *W1r = ff(6), *b1r = ff(7), *W1e = ff(8),
                *att1 = ff(9), *bias1 = ff(10);
    const float *W2l = ff(11), *b2l = ff(12), *W2r = ff(13), *b2r = ff(14), *W2e = ff(15),
                *att2 = ff(16), *bias2 = ff(17);
    const float *W3l = ff(18), *b3l = ff(19), *W3r = ff(20), *b3r = ff(21), *W3e = ff(22),
                *att3 = ff(23), *bias3 = ff(24);
    const float *G1w = ff(25), *G1b = ff(26), *G2w = ff(27), *G2b = ff(28), *Wreg = ff(29),
                *breg = ff(30);

    const int N = in_sizes[0] / 128;  // 40000
    const int E = in_sizes[2] / 2;    // 640000

    char* ws = (char*)d_ws;
    float*  bufA    = (float*)(ws);              // [N,128]
    float*  bufB    = (float*)(ws + 20480000);   // [N,128]
    float*  bufH    = (float*)(ws + 40960000);   // [N,128]
    int2*   elist   = (int2*)(ws + 61440000);    // [E] (src, edge_id)
    int*    row_ptr = (int*)(ws + 66560000);     // [N]
    int*    deg     = (int*)(ws + 66720000);     // [N]
    int*    cursor  = (int*)(ws + 66880000);     // [N]
    int*    excl    = (int*)(ws + 67040000);     // [N]
    int*    parts   = (int*)(ws + 67200000);     // [<=256]
    float*  gate    = (float*)(ws + 67204096);   // [N]
    float*  pooled  = (float*)(ws + 67364096);   // [64,64]
    float4* ea_s    = (float4*)(ws + 67380480);  // [E,32] floats, CSR-ordered (optional)
    const bool sorted_ea = ws_size >= (size_t)67380480 + (size_t)E * 32 * 4;

    auto cdiv = [](int a, int b) { return (a + b - 1) / b; };
    const int NB = cdiv(N, 256);
    const dim3 gemmG(N / 64, 2);
    const int AGGB = cdiv(N, 4);

    // ---- CSR build (once; graph shared by all 3 layers) ----
    k_fill<<<NB, 256, 0, stream>>>((unsigned*)deg, N, 0u);
    k_hist<<<cdiv(E, 256), 256, 0, stream>>>(ei, E, deg);
    k_scan_blocks<<<NB, 256, 0, stream>>>(deg, N, excl, parts);
    k_scan_parts<<<1, 256, 0, stream>>>(parts, NB);
    k_scan_add<<<NB, 256, 0, stream>>>(excl, parts, row_ptr, cursor, N);
    k_scatter<<<cdiv(E, 256), 256, 0, stream>>>(ei, E, cursor, elist);
    if (sorted_ea)
        k_reorder<<<cdiv(E * 8, 256), 256, 0, stream>>>(elist, ea, E, ea_s);

    // ---- layer 1 ----
    k_gemm2<128, 8><<<gemmG, 256, 0, stream>>>(x, W1l, b1l, W1r, b1r, bufA, bufB);
    if (sorted_ea)
        k_agg2<true, true><<<AGGB, 256, 0, stream>>>(bufA, bufB, ea, ea_s, elist, row_ptr, deg, W1e, att1, bias1, bufH, N);
    else
        k_agg2<true, false><<<AGGB, 256, 0, stream>>>(bufA, bufB, ea, ea_s, elist, row_ptr, deg, W1e, att1, bias1, bufH, N);

    // ---- layer 2 ----
    k_gemm2<128, 8><<<gemmG, 256, 0, stream>>>(bufH, W2l, b2l, W2r, b2r, bufA, bufB);
    if (sorted_ea)
        k_agg2<true, true><<<AGGB, 256, 0, stream>>>(bufA, bufB, ea, ea_s, elist, row_ptr, deg, W2e, att2, bias2, bufH, N);
    else
        k_agg2<true, false><<<AGGB, 256, 0, stream>>>(bufA, bufB, ea, ea_s, elist, row_ptr, deg, W2e, att2, bias2, bufH, N);

    // ---- layer 3 ----
    k_gemm2<64, 4><<<gemmG, 256, 0, stream>>>(bufH, W3l, b3l, W3r, b3r, bufA, bufB);
    if (sorted_ea)
        k_agg1<true><<<AGGB, 256, 0, stream>>>(bufA, bufB, ea, ea_s, elist, row_ptr, deg, W3e, att3, bias3, bufH, N);
    else
        k_agg1<false><<<AGGB, 256, 0, stream>>>(bufA, bufB, ea, ea_s, elist, row_ptr, deg, W3e, att3, bias3, bufH, N);

    // ---- attentional pooling + regressor ----
    k_gate<<<N / 64, 256, 0, stream>>>(bufH, G1w, G1b, G2w, G2b, gate, N);
    k_pool<<<64, 256, 0, stream>>>(bufH, gate, batch, pooled, N);
    k_final<<<1, 64, 0, stream>>>(pooled, Wreg, breg, (float*)d_out);
}